// Round 1
// baseline (385.014 us; speedup 1.0000x reference)
//
#include <hip/hip_runtime.h>
#include <math.h>

// CapsuleLayer dynamic routing, fully fused recompute formulation.
// Shapes: x[B=128, J=2048, I=8], W[J, K=32, I, D=16] -> v[B, K, D]
//
// b_t = (sum_{tau<t} v_tau) . u_hat  (linearity, b0 = 0), so we only keep
// vsum[b,k,d] (256 KB) and recompute u_hat per sweep from x and W.

constexpr int Bn = 128;
constexpr int Jn = 2048;
constexpr int In = 8;
constexpr int Kn = 32;
constexpr int Dn = 16;
constexpr int KD = Kn * Dn;          // 512
constexpr int CELLS = Bn * KD;       // 65536

constexpr int JT    = 16;            // j per workgroup
constexpr int NJB   = Jn / JT;       // 128 j-blocks (= #partials per cell)
constexpr int WAVES = 8;
constexpr int BLOCK = WAVES * 64;    // 512 threads
constexpr int BW    = 8;             // batches per wave (s-acc in regs)
constexpr int BGW   = WAVES * BW;    // 64 batches per workgroup
constexpr int NBB   = Bn / BGW;      // 2 b-blocks
constexpr int GRID_SWEEP = NBB * NJB; // 256 workgroups

// PHASE: 0 = uniform c (softmax of zeros = 1/K), 1/2 = softmax(vsum . u_hat)
// ATOMIC=false: write per-(j-block) partials (exactly-once, non-atomic)
// ATOMIC=true : atomicAdd into a single s buffer (small-ws fallback)
template <int PHASE, bool ATOMIC>
__global__ __launch_bounds__(BLOCK, 2)
void sweep_kernel(const float* __restrict__ x, const float* __restrict__ W,
                  const float* __restrict__ vsum, float* __restrict__ sout)
{
    const int jb    = blockIdx.x % NJB;
    const int b0    = (blockIdx.x / NJB) * BGW;
    const int wave  = threadIdx.x >> 6;
    const int lane  = threadIdx.x & 63;
    const int k     = lane >> 1;            // lane pair per output capsule
    const int d0    = (lane & 1) * 8;       // half of D per lane
    const int bbase = b0 + wave * BW;

    float sacc[BW][8];
#pragma unroll
    for (int b = 0; b < BW; ++b)
#pragma unroll
        for (int r = 0; r < 8; ++r) sacc[b][r] = 0.f;

    const int j0 = jb * JT;
    for (int jj = 0; jj < JT; ++jj) {
        const int j = j0 + jj;

        // W[j, k, i, d0..d0+7] fragment -> 64 VGPRs, reused for BW batches
        float Wr[In][8];
        const float* wp = W + ((size_t)j * Kn + k) * (In * Dn) + d0;
#pragma unroll
        for (int i = 0; i < In; ++i) {
            const float4 a  = *reinterpret_cast<const float4*>(wp + i * Dn);
            const float4 b4 = *reinterpret_cast<const float4*>(wp + i * Dn + 4);
            Wr[i][0] = a.x;  Wr[i][1] = a.y;  Wr[i][2] = a.z;  Wr[i][3] = a.w;
            Wr[i][4] = b4.x; Wr[i][5] = b4.y; Wr[i][6] = b4.z; Wr[i][7] = b4.w;
        }

#pragma unroll
        for (int bb = 0; bb < BW; ++bb) {
            const int b = bbase + bb;

            // x[b, j, 0..7] : wave-uniform broadcast load
            const float* xp = x + ((size_t)b * Jn + j) * In;
            const float4 xa = *reinterpret_cast<const float4*>(xp);
            const float4 xb = *reinterpret_cast<const float4*>(xp + 4);
            const float xv[8] = {xa.x, xa.y, xa.z, xa.w, xb.x, xb.y, xb.z, xb.w};

            // u_hat[b, k, j, d0+r] = sum_i x[b,j,i] * W[j,k,i,d0+r]
            float uh[8];
#pragma unroll
            for (int r = 0; r < 8; ++r) {
                float acc = xv[0] * Wr[0][r];
#pragma unroll
                for (int i = 1; i < In; ++i) acc = fmaf(xv[i], Wr[i][r], acc);
                uh[r] = acc;
            }

            if (PHASE == 0) {
                // c is uniform 1/K; fold the 1/32 into the squash kernel
#pragma unroll
                for (int r = 0; r < 8; ++r) sacc[bb][r] += uh[r];
            } else {
                // logit[k] = vsum[b,k,:] . u_hat[b,k,j,:]
                const float* vp = vsum + ((size_t)b * Kn + k) * Dn + d0;
                const float4 va = *reinterpret_cast<const float4*>(vp);
                const float4 vb = *reinterpret_cast<const float4*>(vp + 4);
                float p = va.x * uh[0];
                p = fmaf(va.y, uh[1], p);
                p = fmaf(va.z, uh[2], p);
                p = fmaf(va.w, uh[3], p);
                p = fmaf(vb.x, uh[4], p);
                p = fmaf(vb.y, uh[5], p);
                p = fmaf(vb.z, uh[6], p);
                p = fmaf(vb.w, uh[7], p);
                p += __shfl_xor(p, 1);   // reduce the two d-halves -> full dot

                // softmax over k: masks 2..32 mix only same-parity lanes, so
                // each of the 32 k values is counted exactly once.
                float m = p;
#pragma unroll
                for (int mk = 2; mk <= 32; mk <<= 1)
                    m = fmaxf(m, __shfl_xor(m, mk));
                const float e = __expf(p - m);
                float ssum = e;
#pragma unroll
                for (int mk = 2; mk <= 32; mk <<= 1)
                    ssum += __shfl_xor(ssum, mk);
#if __has_builtin(__builtin_amdgcn_rcpf)
                const float c = e * __builtin_amdgcn_rcpf(ssum);
#else
                const float c = e / ssum;
#endif
#pragma unroll
                for (int r = 0; r < 8; ++r)
                    sacc[bb][r] = fmaf(c, uh[r], sacc[bb][r]);
            }
        }
    }

    // epilogue: dump per-wave s partials
#pragma unroll
    for (int bb = 0; bb < BW; ++bb) {
        const int b = bbase + bb;
        const size_t cell = ((size_t)b * Kn + k) * Dn + d0;
        if (ATOMIC) {
#pragma unroll
            for (int r = 0; r < 8; ++r)
                atomicAdd(sout + cell + r, sacc[bb][r]);
        } else {
            const float4 f0 = make_float4(sacc[bb][0], sacc[bb][1], sacc[bb][2], sacc[bb][3]);
            const float4 f1 = make_float4(sacc[bb][4], sacc[bb][5], sacc[bb][6], sacc[bb][7]);
            float* dst = sout + (size_t)jb * CELLS + cell;
            *reinterpret_cast<float4*>(dst)     = f0;
            *reinterpret_cast<float4*>(dst + 4) = f1;
        }
    }
}

// Reduce partials (or consume the atomic buffer), apply squash, update vsum,
// and on the final phase write v to d_out. 16384 threads, 4 cells each.
template <int PHASE, bool ATOMIC>
__global__ __launch_bounds__(256)
void squash_kernel(float* __restrict__ sbuf, float* __restrict__ vsum,
                   float* __restrict__ outv)
{
    const int t = blockIdx.x * blockDim.x + threadIdx.x;   // 0..16383
    const size_t c4 = (size_t)t * 4;

    float4 s;
    if (ATOMIC) {
        s = *reinterpret_cast<const float4*>(sbuf + c4);
        // re-zero for the next sweep in this launch
        *reinterpret_cast<float4*>(sbuf + c4) = make_float4(0.f, 0.f, 0.f, 0.f);
    } else {
        s = make_float4(0.f, 0.f, 0.f, 0.f);
#pragma unroll 4
        for (int p = 0; p < NJB; ++p) {
            const float4 v = *reinterpret_cast<const float4*>(sbuf + (size_t)p * CELLS + c4);
            s.x += v.x; s.y += v.y; s.z += v.z; s.w += v.w;
        }
    }

    if (PHASE == 0) {  // uniform c = 1/K was folded out of the sweep
        const float sc = 1.f / 32.f;
        s.x *= sc; s.y *= sc; s.z *= sc; s.w *= sc;
    }

    // squash over D=16 -> 4 consecutive threads per (b,k)
    float s2 = s.x * s.x + s.y * s.y + s.z * s.z + s.w * s.w;
    s2 += __shfl_xor(s2, 1);
    s2 += __shfl_xor(s2, 2);
    const float scale = s2 / ((1.f + s2) * sqrtf(s2 + 1e-7f));
    const float4 v4 = make_float4(s.x * scale, s.y * scale, s.z * scale, s.w * scale);

    if (PHASE == 2) {
        *reinterpret_cast<float4*>(outv + c4) = v4;
    } else if (PHASE == 0) {
        *reinterpret_cast<float4*>(vsum + c4) = v4;           // vsum = v0
    } else {
        float4 o = *reinterpret_cast<const float4*>(vsum + c4);
        o.x += v4.x; o.y += v4.y; o.z += v4.z; o.w += v4.w;   // vsum += v1
        *reinterpret_cast<float4*>(vsum + c4) = o;
    }
}

extern "C" void kernel_launch(void* const* d_in, const int* in_sizes, int n_in,
                              void* d_out, int out_size, void* d_ws, size_t ws_size,
                              hipStream_t stream)
{
    const float* x = (const float*)d_in[0];
    const float* W = (const float*)d_in[1];
    float* out = (float*)d_out;

    const size_t partial_bytes = (size_t)NJB * CELLS * sizeof(float);  // 32 MB
    const size_t vsum_bytes    = (size_t)CELLS * sizeof(float);        // 256 KB

    const dim3 gs(GRID_SWEEP), bs(BLOCK);
    const dim3 gq(CELLS / 4 / 256), bq(256);

    if (ws_size >= partial_bytes + vsum_bytes) {
        float* partial = (float*)d_ws;
        float* vsum    = (float*)((char*)d_ws + partial_bytes);
        sweep_kernel<0, false><<<gs, bs, 0, stream>>>(x, W, vsum, partial);
        squash_kernel<0, false><<<gq, bq, 0, stream>>>(partial, vsum, out);
        sweep_kernel<1, false><<<gs, bs, 0, stream>>>(x, W, vsum, partial);
        squash_kernel<1, false><<<gq, bq, 0, stream>>>(partial, vsum, out);
        sweep_kernel<2, false><<<gs, bs, 0, stream>>>(x, W, vsum, partial);
        squash_kernel<2, false><<<gq, bq, 0, stream>>>(partial, vsum, out);
    } else {
        // small-workspace fallback: single 256 KB accumulator + atomics
        float* sbuf = (float*)d_ws;
        float* vsum = (float*)((char*)d_ws + vsum_bytes);
        hipMemsetAsync(sbuf, 0, vsum_bytes, stream);
        sweep_kernel<0, true><<<gs, bs, 0, stream>>>(x, W, vsum, sbuf);
        squash_kernel<0, true><<<gq, bq, 0, stream>>>(sbuf, vsum, out);
        sweep_kernel<1, true><<<gs, bs, 0, stream>>>(x, W, vsum, sbuf);
        squash_kernel<1, true><<<gq, bq, 0, stream>>>(sbuf, vsum, out);
        sweep_kernel<2, true><<<gs, bs, 0, stream>>>(x, W, vsum, sbuf);
        squash_kernel<2, true><<<gq, bq, 0, stream>>>(sbuf, vsum, out);
    }
}